// Round 6
// baseline (42.288 us; speedup 1.0000x reference)
//
#include <hip/hip_runtime.h>
#include <hip/hip_bf16.h>
#include <math.h>

#define NPIX 65536

typedef short short8 __attribute__((ext_vector_type(8)));
typedef float f32x4 __attribute__((ext_vector_type(4)));

// ---- static device scratch (fully rewritten every call) ----
__device__ int            g_kp_idx[2048];
__device__ __hip_bfloat16 g_dbf[2048 * 192];   // all descriptors, bf16
__device__ __hip_bfloat16 g_dw0[1024 * 192];   // side-1 desc * fc_w[0,:], bf16
__device__ __hip_bfloat16 g_dw1[1024 * 192];   // side-1 desc * fc_w[1,:], bf16

__device__ __forceinline__ unsigned long long u64min(unsigned long long a, unsigned long long b) {
    return a < b ? a : b;
}
__device__ __forceinline__ unsigned long long u64max(unsigned long long a, unsigned long long b) {
    return a > b ? a : b;
}

// ---------------- phase 1: fused NMS + top-512 (logit domain) -------------
// grid 4 (one block per image) x 1024 threads; thread t owns 8x8 window t.
// sigmoid is monotone -> argmax & sort on raw logits; sigmoid only at emit.
__global__ __launch_bounds__(1024) void nms_topk_kernel(
        const float* __restrict__ hm1, const float* __restrict__ hm2,
        float* __restrict__ out) {
    __shared__ unsigned long long keys[1024];
    int img = blockIdx.x;             // hm*2 + b
    int t = threadIdx.x;              // window id 0..1023
    int b = img & 1, hmid = img >> 1;
    const float* hp = (hmid ? hm2 : hm1) + b * NPIX;

    // --- NMS for window t: row-major scan, earliest-index tie-break
    int wy = t >> 5, wx = t & 31;
    const float* wp = hp + wy * 8 * 256 + wx * 8;
    float mv = -3.4e38f;
    int mi = 0;
    #pragma unroll
    for (int r = 0; r < 8; ++r) {
        float4 v0 = *reinterpret_cast<const float4*>(wp + r * 256);
        float4 v1 = *reinterpret_cast<const float4*>(wp + r * 256 + 4);
        float s[8] = {v0.x, v0.y, v0.z, v0.w, v1.x, v1.y, v1.z, v1.w};
        int rowbase = (wy * 8 + r) * 256 + wx * 8;
        #pragma unroll
        for (int cidx = 0; cidx < 8; ++cidx) {
            if (s[cidx] > mv) { mv = s[cidx]; mi = rowbase + cidx; }
        }
    }
    int ay = mi >> 8, ax = mi & 255;
    bool interior = (ay >= 10 && ay < 246 && ax >= 10 && ax < 246);
    unsigned int ub = __float_as_uint(mv);
    unsigned int mk = (ub & 0x80000000u) ? ~ub : (ub | 0x80000000u);
    if (!interior) mk = 0u;
    // ascending sort key: smallest = largest value, ties -> smallest idx
    unsigned long long k = ((unsigned long long)(~mk) << 32) |
                           (unsigned long long)(unsigned int)mi;

    // --- bitonic sort, ascending: strides<=32 via shfl, >=64 via LDS
    for (int size = 2; size <= 1024; size <<= 1) {
        for (int stride = size >> 1; stride >= 1; stride >>= 1) {
            bool dir_up = ((t & size) == 0);
            unsigned long long pk;
            if (stride >= 64) {
                __syncthreads();
                keys[t] = k;
                __syncthreads();
                pk = keys[t ^ stride];
            } else {
                pk = __shfl_xor(k, stride);
            }
            bool low = ((t & stride) == 0);
            k = ((low == dir_up)) ? u64min(k, pk) : u64max(k, pk);
        }
    }

    if (t < 512) {
        unsigned int fidx = (unsigned int)(k & 0xFFFFFFFFull);
        unsigned int mk2 = ~(unsigned int)(k >> 32);
        unsigned int lb = (mk2 & 0x80000000u) ? (mk2 ^ 0x80000000u) : ~mk2;
        float logit = __uint_as_float(lb);
        float v = 1.0f / (1.0f + expf(-logit));
        int row = fidx >> 8, col = fidx & 255;
        float gx = 2.0f * (float)col / 255.0f - 1.0f;
        float gy = 2.0f * (float)row / 255.0f - 1.0f;
        out[hmid * 1024 + b * 512 + t] = v;
        float* lm = out + (hmid ? 4096 : 2048) + (size_t)(b * 512 + t) * 2;
        lm[0] = gx; lm[1] = gy;
        g_kp_idx[img * 512 + t] = (int)fidx;
    }
}

// ---------------- phase 2: descriptor build ------------------------------
// grid 1024 x 256 thr, role = bid&1 (interleaved for overlap):
//  role 0 (512 blocks): half-res channel sweep. Block = (img, c): stage the
//    whole 128x128 channel image in LDS (64 KB, coalesced float4), then 512
//    keypoints bilinear from LDS. Coalesced 67 MB instead of 33 MB random.
//  role 1 (512 blocks): full-res direct gather, thread = (kp, c).
__global__ __launch_bounds__(256) void desc_kernel(
        const float* __restrict__ f1a, const float* __restrict__ f1b,
        const float* __restrict__ f2a, const float* __restrict__ f2b,
        const float* __restrict__ fcw) {
    __shared__ float img_lds[16384];
    int bid = blockIdx.x;
    int sub = bid >> 1;
    int t = threadIdx.x;
    if ((bid & 1) == 0) {
        // ---- half-res sweep: img = sub>>7, channel c = sub&127
        int img = sub >> 7, c = sub & 127;
        int b = img & 1, hmid = img >> 1;
        const float4* src = reinterpret_cast<const float4*>(
            (hmid ? f2b : f1b) + (size_t)(b * 128 + c) * 16384);
        float4* dst = reinterpret_cast<float4*>(img_lds);
        #pragma unroll
        for (int i = 0; i < 16; ++i) dst[t + 256 * i] = src[t + 256 * i];
        __syncthreads();
        float w0 = fcw[64 + c], w1 = fcw[192 + 64 + c];
        #pragma unroll
        for (int r = 0; r < 2; ++r) {
            int kpl = t * 2 + r;                 // 0..511
            int kp = img * 512 + kpl;
            int fidx = g_kp_idx[kp];
            int row = fidx >> 8, col = fidx & 255;
            float gx = 2.0f * (float)col / 255.0f - 1.0f;
            float gy = 2.0f * (float)row / 255.0f - 1.0f;
            float ix = (gx + 1.0f) * 0.5f * 127.0f;
            float iy = (gy + 1.0f) * 0.5f * 127.0f;
            int x0 = (int)ix, y0 = (int)iy;      // interior: trunc == floor
            float wx = ix - (float)x0, wy = iy - (float)y0;
            const float* p = img_lds + y0 * 128 + x0;
            float val = p[0] * (1 - wx) * (1 - wy) + p[1] * wx * (1 - wy)
                      + p[128] * (1 - wx) * wy    + p[129] * wx * wy;
            g_dbf[(size_t)kp * 192 + 64 + c] = __float2bfloat16(val);
            if (img < 2) {
                g_dw0[(size_t)kp * 192 + 64 + c] = __float2bfloat16(val * w0);
                g_dw1[(size_t)kp * 192 + 64 + c] = __float2bfloat16(val * w1);
            }
        }
    } else {
        // ---- full-res gather: img = sub>>7, kp-group = sub&127
        int img = sub >> 7, kpg = sub & 127;
        int b = img & 1, hmid = img >> 1;
        int kpl = kpg * 4 + (t >> 6);
        int c = t & 63;
        int kp = img * 512 + kpl;
        int fidx = g_kp_idx[kp];
        const float* fa = (hmid ? f2a : f1a) + (size_t)(b * 64 + c) * 65536;
        float val = fa[fidx];
        g_dbf[(size_t)kp * 192 + c] = __float2bfloat16(val);
        if (img < 2) {
            g_dw0[(size_t)kp * 192 + c] = __float2bfloat16(val * fcw[c]);
            g_dw1[(size_t)kp * 192 + c] = __float2bfloat16(val * fcw[192 + c]);
        }
    }
}

// ---------------- phase 3: matching via MFMA + fused norm ----------------
// grid (8, 32, 2) x 256 thr; one wave per 16x16 output tile.
// Prologue: deterministically recompute inv/||n||^2 for the tile's 16 rows
// + 64 cols from bf16 descriptors (identical partition in every block).
__global__ __launch_bounds__(256) void match_kernel(
        const float* __restrict__ fcb, float* __restrict__ out) {
    __shared__ float inv1_s[16], nn1_s[16], inv2_s[64], nn2_s[64];
    int t = threadIdx.x;
    int w = t >> 6, lane = t & 63;
    int b = blockIdx.z;
    int k1base = blockIdx.y * 16;
    int k2base = blockIdx.x * 64;

    // pass A: 64 k2 slots x 4 threads (48 channels each)
    {
        int slot = t >> 2, part = t & 3;
        const __hip_bfloat16* dp = g_dbf +
            (size_t)((2 + b) * 512 + k2base + slot) * 192 + part * 48;
        float sq = 0.f;
        #pragma unroll
        for (int i = 0; i < 48; ++i) {
            float v = __bfloat162float(dp[i]);
            sq += v * v;
        }
        sq += __shfl_xor(sq, 1);
        sq += __shfl_xor(sq, 2);
        if (part == 0) {
            float nrm = sqrtf(sq);
            float inv = 1.0f / (1e-6f + nrm);
            inv2_s[slot] = inv;
            nn2_s[slot] = sq * inv * inv;
        }
    }
    // pass B: 16 k1 slots x 16 threads (12 channels each)
    {
        int slot = t >> 4, part = t & 15;
        const __hip_bfloat16* dp = g_dbf +
            (size_t)(b * 512 + k1base + slot) * 192 + part * 12;
        float sq = 0.f;
        #pragma unroll
        for (int i = 0; i < 12; ++i) {
            float v = __bfloat162float(dp[i]);
            sq += v * v;
        }
        sq += __shfl_xor(sq, 1);
        sq += __shfl_xor(sq, 2);
        sq += __shfl_xor(sq, 4);
        sq += __shfl_xor(sq, 8);
        if (part == 0) {
            float nrm = sqrtf(sq);
            float inv = 1.0f / (1e-6f + nrm);
            inv1_s[slot] = inv;
            nn1_s[slot] = sq * inv * inv;
        }
    }
    __syncthreads();

    int k2w = k2base + w * 16;
    int r1 = k1base + (lane & 15);
    int r2 = k2w + (lane & 15);
    int koff = (lane >> 4) * 8;

    const __hip_bfloat16* pA  = g_dbf + (size_t)(b * 512 + r1) * 192 + koff;
    const __hip_bfloat16* pW0 = g_dw0 + (size_t)(b * 512 + r1) * 192 + koff;
    const __hip_bfloat16* pW1 = g_dw1 + (size_t)(b * 512 + r1) * 192 + koff;
    const __hip_bfloat16* pB  = g_dbf + (size_t)((2 + b) * 512 + r2) * 192 + koff;

    f32x4 accd = {0.f, 0.f, 0.f, 0.f};
    f32x4 acc0 = {0.f, 0.f, 0.f, 0.f};
    f32x4 acc1 = {0.f, 0.f, 0.f, 0.f};
    #pragma unroll
    for (int kc = 0; kc < 6; ++kc) {
        short8 a  = *reinterpret_cast<const short8*>(pA  + kc * 32);
        short8 a0 = *reinterpret_cast<const short8*>(pW0 + kc * 32);
        short8 a1 = *reinterpret_cast<const short8*>(pW1 + kc * 32);
        short8 bb = *reinterpret_cast<const short8*>(pB  + kc * 32);
        accd = __builtin_amdgcn_mfma_f32_16x16x32_bf16(a,  bb, accd, 0, 0, 0);
        acc0 = __builtin_amdgcn_mfma_f32_16x16x32_bf16(a0, bb, acc0, 0, 0, 0);
        acc1 = __builtin_amdgcn_mfma_f32_16x16x32_bf16(a1, bb, acc1, 0, 0, 0);
    }

    float bb0 = fcb[0], bb1 = fcb[1];
    int colc = lane & 15;
    int k2 = k2w + colc;
    float inv2 = inv2_s[w * 16 + colc];
    float nn2  = nn2_s[w * 16 + colc];
    #pragma unroll
    for (int j = 0; j < 4; ++j) {
        int s1 = (lane >> 4) * 4 + j;
        int k1 = k1base + s1;
        float inv1 = inv1_s[s1];
        float nn1  = nn1_s[s1];
        size_t sidx = (size_t)(b * 512 + k1) * 512 + k2;
        float2 sc = make_float2(acc0[j] + bb0, acc1[j] + bb1);
        *reinterpret_cast<float2*>(out + 6144 + sidx * 2) = sc;
        float arg = nn1 + nn2 - 2.0f * inv1 * inv2 * accd[j];
        out[1054720 + sidx] = sqrtf(fmaxf(arg, 0.0f));
    }
}

extern "C" void kernel_launch(void* const* d_in, const int* in_sizes, int n_in,
                              void* d_out, int out_size, void* d_ws, size_t ws_size,
                              hipStream_t stream) {
    const float* hm1 = (const float*)d_in[0];
    const float* hm2 = (const float*)d_in[1];
    const float* f1a = (const float*)d_in[2];
    const float* f1b = (const float*)d_in[3];
    const float* f2a = (const float*)d_in[4];
    const float* f2b = (const float*)d_in[5];
    const float* fcw = (const float*)d_in[6];
    const float* fcb = (const float*)d_in[7];
    float* out = (float*)d_out;
    (void)d_ws; (void)ws_size;

    nms_topk_kernel<<<4, 1024, 0, stream>>>(hm1, hm2, out);
    desc_kernel<<<1024, 256, 0, stream>>>(f1a, f1b, f2a, f2b, fcw);
    dim3 g(8, 32, 2);
    match_kernel<<<g, 256, 0, stream>>>(fcb, out);
}

// Round 7
// 39.733 us; speedup vs baseline: 1.0643x; 1.0643x over previous
//
#include <hip/hip_runtime.h>
#include <hip/hip_bf16.h>
#include <math.h>

#define NPIX 65536

typedef short short8 __attribute__((ext_vector_type(8)));
typedef float f32x4 __attribute__((ext_vector_type(4)));

// ---- static device scratch (fully rewritten every call) ----
__device__ int            g_kp_idx[2048];
__device__ float          g_invws[2048];
__device__ float          g_nnws[2048];
__device__ __hip_bfloat16 g_dbf[2048 * 192];   // all descriptors, bf16
__device__ __hip_bfloat16 g_dw0[1024 * 192];   // side-1 desc * fc_w[0,:], bf16
__device__ __hip_bfloat16 g_dw1[1024 * 192];   // side-1 desc * fc_w[1,:], bf16

__device__ __forceinline__ unsigned long long u64min(unsigned long long a, unsigned long long b) {
    return a < b ? a : b;
}
__device__ __forceinline__ unsigned long long u64max(unsigned long long a, unsigned long long b) {
    return a > b ? a : b;
}

// ---------------- phase 1: fused NMS + top-512 (logit domain) -------------
// grid 4 (one block per image) x 1024 threads; thread t owns 8x8 window t.
// sigmoid is monotone -> argmax & sort on raw logits; sigmoid only at emit.
__global__ __launch_bounds__(1024) void nms_topk_kernel(
        const float* __restrict__ hm1, const float* __restrict__ hm2,
        float* __restrict__ out) {
    __shared__ unsigned long long keys[1024];
    int img = blockIdx.x;             // hm*2 + b
    int t = threadIdx.x;              // window id 0..1023
    int b = img & 1, hmid = img >> 1;
    const float* hp = (hmid ? hm2 : hm1) + b * NPIX;

    // --- NMS for window t: row-major scan, earliest-index tie-break
    int wy = t >> 5, wx = t & 31;
    const float* wp = hp + wy * 8 * 256 + wx * 8;
    float mv = -3.4e38f;
    int mi = 0;
    #pragma unroll
    for (int r = 0; r < 8; ++r) {
        float4 v0 = *reinterpret_cast<const float4*>(wp + r * 256);
        float4 v1 = *reinterpret_cast<const float4*>(wp + r * 256 + 4);
        float s[8] = {v0.x, v0.y, v0.z, v0.w, v1.x, v1.y, v1.z, v1.w};
        int rowbase = (wy * 8 + r) * 256 + wx * 8;
        #pragma unroll
        for (int cidx = 0; cidx < 8; ++cidx) {
            if (s[cidx] > mv) { mv = s[cidx]; mi = rowbase + cidx; }
        }
    }
    int ay = mi >> 8, ax = mi & 255;
    bool interior = (ay >= 10 && ay < 246 && ax >= 10 && ax < 246);
    unsigned int ub = __float_as_uint(mv);
    unsigned int mk = (ub & 0x80000000u) ? ~ub : (ub | 0x80000000u);
    if (!interior) mk = 0u;
    // ascending sort key: smallest = largest value, ties -> smallest idx
    unsigned long long k = ((unsigned long long)(~mk) << 32) |
                           (unsigned long long)(unsigned int)mi;

    // --- bitonic sort, ascending: strides<=32 via shfl, >=64 via LDS
    for (int size = 2; size <= 1024; size <<= 1) {
        for (int stride = size >> 1; stride >= 1; stride >>= 1) {
            bool dir_up = ((t & size) == 0);
            unsigned long long pk;
            if (stride >= 64) {
                __syncthreads();
                keys[t] = k;
                __syncthreads();
                pk = keys[t ^ stride];
            } else {
                pk = __shfl_xor(k, stride);
            }
            bool low = ((t & stride) == 0);
            k = ((low == dir_up)) ? u64min(k, pk) : u64max(k, pk);
        }
    }

    if (t < 512) {
        unsigned int fidx = (unsigned int)(k & 0xFFFFFFFFull);
        unsigned int mk2 = ~(unsigned int)(k >> 32);
        unsigned int lb = (mk2 & 0x80000000u) ? (mk2 ^ 0x80000000u) : ~mk2;
        float logit = __uint_as_float(lb);
        float v = 1.0f / (1.0f + expf(-logit));
        int row = fidx >> 8, col = fidx & 255;
        float gx = 2.0f * (float)col / 255.0f - 1.0f;
        float gy = 2.0f * (float)row / 255.0f - 1.0f;
        out[hmid * 1024 + b * 512 + t] = v;
        float* lm = out + (hmid ? 4096 : 2048) + (size_t)(b * 512 + t) * 2;
        lm[0] = gx; lm[1] = gy;
        g_kp_idx[img * 512 + t] = (int)fidx;
    }
}

// ---------------- phase 2: descriptor gather, 1 load/thread --------------
// grid 2048 (one block per keypoint) x 576 threads:
//   t in [0,64):   full-res channel t, exact-pixel direct gather (1 load)
//   t in [64,576): corner (t-64)&3 of half-res channel (t-64)>>2 (1 load),
//                  weight-multiplied, combined via 2 shfl_xor (corners of a
//                  channel sit in 4 adjacent lanes of one wave).
// Then norm reduce over the 192 combined values via LDS.
__global__ __launch_bounds__(576) void desc_kernel(
        const float* __restrict__ f1a, const float* __restrict__ f1b,
        const float* __restrict__ f2a, const float* __restrict__ f2b,
        const float* __restrict__ fcw) {
    __shared__ float vals[192];
    int kp = blockIdx.x;                     // 0..2047
    int t = threadIdx.x;
    int img = kp >> 9, b = img & 1, hmid = img >> 1;
    int fidx = g_kp_idx[kp];
    int row = fidx >> 8, col = fidx & 255;

    if (t < 64) {
        // full-res half: exact pixel -> direct gather
        const float* fa = (hmid ? f2a : f1a) + (size_t)(b * 64 + t) * 65536;
        vals[t] = fa[fidx];
    } else {
        int ch = (t - 64) >> 2;              // 0..127
        int corner = (t - 64) & 3;
        // bilinear setup (identical arithmetic to reference)
        float gx = 2.0f * (float)col / 255.0f - 1.0f;
        float gy = 2.0f * (float)row / 255.0f - 1.0f;
        float ix = (gx + 1.0f) * 0.5f * 127.0f;
        float iy = (gy + 1.0f) * 0.5f * 127.0f;
        int x0 = (int)ix, y0 = (int)iy;      // interior: trunc == floor
        float wx = ix - (float)x0, wy = iy - (float)y0;
        int xx = x0 + (corner & 1);
        int yy = y0 + (corner >> 1);
        float w = ((corner & 1) ? wx : 1.0f - wx) *
                  ((corner >> 1) ? wy : 1.0f - wy);
        const float* fb = (hmid ? f2b : f1b) + (size_t)(b * 128 + ch) * 16384;
        float v = fb[yy * 128 + xx] * w;
        v += __shfl_xor(v, 1);
        v += __shfl_xor(v, 2);
        if (corner == 0) vals[64 + ch] = v;
    }
    __syncthreads();

    // writes + norm from the combined values (threads 0..63 only)
    if (t < 64) {
        float v0 = vals[t], v1 = vals[t + 64], v2 = vals[t + 128];
        __hip_bfloat16* dp = g_dbf + (size_t)kp * 192;
        dp[t]       = __float2bfloat16(v0);
        dp[t + 64]  = __float2bfloat16(v1);
        dp[t + 128] = __float2bfloat16(v2);
        if (kp < 1024) {
            __hip_bfloat16* q0 = g_dw0 + (size_t)kp * 192;
            __hip_bfloat16* q1 = g_dw1 + (size_t)kp * 192;
            q0[t]       = __float2bfloat16(v0 * fcw[t]);
            q0[t + 64]  = __float2bfloat16(v1 * fcw[t + 64]);
            q0[t + 128] = __float2bfloat16(v2 * fcw[t + 128]);
            q1[t]       = __float2bfloat16(v0 * fcw[192 + t]);
            q1[t + 64]  = __float2bfloat16(v1 * fcw[192 + t + 64]);
            q1[t + 128] = __float2bfloat16(v2 * fcw[192 + t + 128]);
        }
        float sq = v0 * v0 + v1 * v1 + v2 * v2;
        #pragma unroll
        for (int m = 1; m <= 32; m <<= 1) sq += __shfl_xor(sq, m);
        if (t == 0) {
            float nrm = sqrtf(sq);
            float inv = 1.0f / (1e-6f + nrm);
            g_invws[kp] = inv;
            g_nnws[kp] = sq * inv * inv;   // ||n||^2
        }
    }
}

// ---------------- phase 3: pairwise matching via MFMA --------------------
// C = D1 * D2^T with three accumulator sets (dot, score0, score1).
// grid (8, 32, 2) x 256 thr; one wave per 16x16 output tile; no LDS.
__global__ __launch_bounds__(256) void match_kernel(
        const float* __restrict__ fcb, float* __restrict__ out) {
    int t = threadIdx.x;
    int w = t >> 6, lane = t & 63;
    int b = blockIdx.z;
    int k1base = blockIdx.y * 16;
    int k2base = blockIdx.x * 64 + w * 16;
    int r1 = k1base + (lane & 15);
    int r2 = k2base + (lane & 15);
    int koff = (lane >> 4) * 8;

    const __hip_bfloat16* pA  = g_dbf + (size_t)(b * 512 + r1) * 192 + koff;
    const __hip_bfloat16* pW0 = g_dw0 + (size_t)(b * 512 + r1) * 192 + koff;
    const __hip_bfloat16* pW1 = g_dw1 + (size_t)(b * 512 + r1) * 192 + koff;
    const __hip_bfloat16* pB  = g_dbf + (size_t)((2 + b) * 512 + r2) * 192 + koff;

    f32x4 accd = {0.f, 0.f, 0.f, 0.f};
    f32x4 acc0 = {0.f, 0.f, 0.f, 0.f};
    f32x4 acc1 = {0.f, 0.f, 0.f, 0.f};
    #pragma unroll
    for (int kc = 0; kc < 6; ++kc) {
        short8 a  = *reinterpret_cast<const short8*>(pA  + kc * 32);
        short8 a0 = *reinterpret_cast<const short8*>(pW0 + kc * 32);
        short8 a1 = *reinterpret_cast<const short8*>(pW1 + kc * 32);
        short8 bb = *reinterpret_cast<const short8*>(pB  + kc * 32);
        accd = __builtin_amdgcn_mfma_f32_16x16x32_bf16(a,  bb, accd, 0, 0, 0);
        acc0 = __builtin_amdgcn_mfma_f32_16x16x32_bf16(a0, bb, acc0, 0, 0, 0);
        acc1 = __builtin_amdgcn_mfma_f32_16x16x32_bf16(a1, bb, acc1, 0, 0, 0);
    }

    float bb0 = fcb[0], bb1 = fcb[1];
    int colc = lane & 15;
    int k2 = k2base + colc;
    float inv2 = g_invws[(2 + b) * 512 + k2];
    float nn2  = g_nnws[(2 + b) * 512 + k2];
    #pragma unroll
    for (int j = 0; j < 4; ++j) {
        int k1 = k1base + (lane >> 4) * 4 + j;
        float inv1 = g_invws[b * 512 + k1];
        float nn1  = g_nnws[b * 512 + k1];
        size_t sidx = (size_t)(b * 512 + k1) * 512 + k2;
        float2 sc = make_float2(acc0[j] + bb0, acc1[j] + bb1);
        *reinterpret_cast<float2*>(out + 6144 + sidx * 2) = sc;
        float arg = nn1 + nn2 - 2.0f * inv1 * inv2 * accd[j];
        out[1054720 + sidx] = sqrtf(fmaxf(arg, 0.0f));
    }
}

extern "C" void kernel_launch(void* const* d_in, const int* in_sizes, int n_in,
                              void* d_out, int out_size, void* d_ws, size_t ws_size,
                              hipStream_t stream) {
    const float* hm1 = (const float*)d_in[0];
    const float* hm2 = (const float*)d_in[1];
    const float* f1a = (const float*)d_in[2];
    const float* f1b = (const float*)d_in[3];
    const float* f2a = (const float*)d_in[4];
    const float* f2b = (const float*)d_in[5];
    const float* fcw = (const float*)d_in[6];
    const float* fcb = (const float*)d_in[7];
    float* out = (float*)d_out;
    (void)d_ws; (void)ws_size;

    nms_topk_kernel<<<4, 1024, 0, stream>>>(hm1, hm2, out);
    desc_kernel<<<2048, 576, 0, stream>>>(f1a, f1b, f2a, f2b, fcw);
    dim3 g(8, 32, 2);
    match_kernel<<<g, 256, 0, stream>>>(fcb, out);
}